// Round 4
// baseline (466.927 us; speedup 1.0000x reference)
//
#include <hip/hip_runtime.h>

#define T_STEPS 512
#define HID 128

typedef float vf16 __attribute__((ext_vector_type(16)));
typedef float vf4  __attribute__((ext_vector_type(4)));

// One block per batch row. 128 threads = 2 waves.
// Thread j owns output h[j]. W_hh row j lives in 8 NAMED ext_vector_type(16)
// SSA values (r2/r3 showed a plain float[128] array is never SROA'd -> the
// compiler re-loaded W every timestep; VGPR_Count was stuck at 72).
// Per step: h exchanged via 1KB double-buffered LDS (1 barrier/step),
// broadcast across the wave with v_readlane (VALU pipe). x[] preloaded to LDS.
__global__ __launch_bounds__(128, 2)
void rnn_scan_kernel(const float* __restrict__ x,
                     const float* __restrict__ W_ih,
                     const float* __restrict__ W_hh,
                     const float* __restrict__ b_ih,
                     const float* __restrict__ b_hh,
                     const float* __restrict__ W_out,
                     const float* __restrict__ b_out,
                     float* __restrict__ y,
                     int T)
{
    const int b    = blockIdx.x;
    const int j    = threadIdx.x;      // 0..127 : which h element this thread produces
    const int lane = j & 63;
    const int wid  = j >> 6;           // 0: j in [0,64), 1: j in [64,128)

    __shared__ float hbuf[2][HID];
    __shared__ float xs[T_STEPS];
    __shared__ float red[2];

    // --- W_hh row j -> 8 named 16-wide vector registers (pure SSA, no memory)
    const float* wrow = W_hh + j * HID;
    vf16 w0 = *(const vf16*)(wrow +   0);
    vf16 w1 = *(const vf16*)(wrow +  16);
    vf16 w2 = *(const vf16*)(wrow +  32);
    vf16 w3 = *(const vf16*)(wrow +  48);
    vf16 w4 = *(const vf16*)(wrow +  64);
    vf16 w5 = *(const vf16*)(wrow +  80);
    vf16 w6 = *(const vf16*)(wrow +  96);
    vf16 w7 = *(const vf16*)(wrow + 112);

    const float wih_j  = W_ih[j];
    const float bias_j = b_ih[j] + b_hh[j];

    // --- x for this sequence -> LDS (one coalesced pass; removes the per-step
    // global load + vmcnt wait from the recurrence critical path)
    const float* xrow = x + (size_t)b * T;   // x is [B, T, 1]
    #pragma unroll
    for (int c = 0; c < T_STEPS / HID; ++c)
        xs[j + c * HID] = xrow[j + c * HID];

    float hA = 0.0f;   // h[j] for this thread (h0 = 0)

    // 16 broadcast+FMA pairs against one weight vector; 4 accumulator chains
#define DOT16(WV, SRC, BASE)                                                  \
    _Pragma("unroll")                                                         \
    for (int kk = 0; kk < 16; ++kk) {                                         \
        float s = __int_as_float(__builtin_amdgcn_readlane((SRC), (BASE)+kk));\
        acc[kk & 3] = fmaf(s, (WV)[kk], acc[kk & 3]);                         \
    }

    for (int t = 0; t < T; ++t) {
        // publish own half, fetch opposite half (double buffer -> 1 barrier/step)
        hbuf[t & 1][j] = hA;
        __syncthreads();
        const float hO = hbuf[t & 1][j ^ 64];
        const float xt = xs[t];

        // wave 0 lanes hold h[0..63] in hA, h[64..127] in hO; wave 1 swapped.
        const int src_lo = __float_as_int(wid ? hO : hA); // lane k has h[k]
        const int src_hi = __float_as_int(wid ? hA : hO); // lane k has h[64+k]

        vf4 acc;
        acc[0] = fmaf(xt, wih_j, bias_j);
        acc[1] = 0.0f; acc[2] = 0.0f; acc[3] = 0.0f;

        DOT16(w0, src_lo,  0)
        DOT16(w1, src_lo, 16)
        DOT16(w2, src_lo, 32)
        DOT16(w3, src_lo, 48)
        DOT16(w4, src_hi,  0)
        DOT16(w5, src_hi, 16)
        DOT16(w6, src_hi, 32)
        DOT16(w7, src_hi, 48)

        const float a = (acc[0] + acc[1]) + (acc[2] + acc[3]);
        // tanh(a) = 1 - 2/(exp(2a)+1), exp via v_exp_f32
        const float e = __expf(2.0f * a);
        hA = 1.0f - __fdividef(2.0f, e + 1.0f);
        // e==inf -> 2/inf = 0 -> 1 ; e==0 -> 1-2 = -1 : saturation correct
    }
#undef DOT16

    // --- y[b] = sum_j W_out[j] * h_last[j] + b_out
    float v = hA * W_out[j];
    #pragma unroll
    for (int off = 32; off >= 1; off >>= 1)
        v += __shfl_xor(v, off, 64);
    if (lane == 0) red[wid] = v;
    __syncthreads();
    if (j == 0) y[b] = red[0] + red[1] + b_out[0];
}

extern "C" void kernel_launch(void* const* d_in, const int* in_sizes, int n_in,
                              void* d_out, int out_size, void* d_ws, size_t ws_size,
                              hipStream_t stream)
{
    const float* x     = (const float*)d_in[0];
    const float* W_ih  = (const float*)d_in[1];
    const float* W_hh  = (const float*)d_in[2];
    const float* b_ih  = (const float*)d_in[3];
    const float* b_hh  = (const float*)d_in[4];
    const float* W_out = (const float*)d_in[5];
    const float* b_out = (const float*)d_in[6];
    float* y = (float*)d_out;

    const int T = T_STEPS;
    const int B = in_sizes[0] / T;   // x has B*T*1 elements

    rnn_scan_kernel<<<B, HID, 0, stream>>>(x, W_ih, W_hh, b_ih, b_hh,
                                           W_out, b_out, y, T);
}

// Round 5
// 454.183 us; speedup vs baseline: 1.0281x; 1.0281x over previous
//
#include <hip/hip_runtime.h>

#define T_STEPS 512
#define HID 128

typedef float vf16 __attribute__((ext_vector_type(16)));
typedef float vf4  __attribute__((ext_vector_type(4)));

// One block per batch row. 128 threads = 2 waves.
// Thread j owns output h[j]; W_hh row j in 8 named vf16 SSA values.
// KEY FIX (r4 post-mortem): amdgpu_waves_per_eu(2,2) caps the RA's occupancy
// target. Without it, the RA "spills" the 128 weight VGPRs to AGPRs to chase
// 6 waves/EU (which the grid can never reach) and re-reads them every step
// (~128 extra v_accvgpr_read per step = the gap from 280->448 instr/step).
__global__ __launch_bounds__(128)
__attribute__((amdgpu_waves_per_eu(2, 2)))
void rnn_scan_kernel(const float* __restrict__ x,
                     const float* __restrict__ W_ih,
                     const float* __restrict__ W_hh,
                     const float* __restrict__ b_ih,
                     const float* __restrict__ b_hh,
                     const float* __restrict__ W_out,
                     const float* __restrict__ b_out,
                     float* __restrict__ y,
                     int T)
{
    const int b    = blockIdx.x;
    const int j    = threadIdx.x;      // 0..127 : which h element this thread produces
    const int lane = j & 63;
    const int wid  = j >> 6;           // 0: j in [0,64), 1: j in [64,128)

    __shared__ float hbuf[2][HID];
    __shared__ float xs[T_STEPS];
    __shared__ float red[2];

    // --- W_hh row j -> 8 named 16-wide vector registers (pure SSA, no memory)
    const float* wrow = W_hh + j * HID;
    vf16 w0 = *(const vf16*)(wrow +   0);
    vf16 w1 = *(const vf16*)(wrow +  16);
    vf16 w2 = *(const vf16*)(wrow +  32);
    vf16 w3 = *(const vf16*)(wrow +  48);
    vf16 w4 = *(const vf16*)(wrow +  64);
    vf16 w5 = *(const vf16*)(wrow +  80);
    vf16 w6 = *(const vf16*)(wrow +  96);
    vf16 w7 = *(const vf16*)(wrow + 112);

    const float wih_j  = W_ih[j];
    const float bias_j = b_ih[j] + b_hh[j];

    // --- x for this sequence -> LDS (one coalesced pass)
    const float* xrow = x + (size_t)b * T;   // x is [B, T, 1]
    #pragma unroll
    for (int c = 0; c < T_STEPS / HID; ++c)
        xs[j + c * HID] = xrow[j + c * HID];

    float hA = 0.0f;   // h[j] for this thread (h0 = 0)

    // 16 broadcast+FMA pairs against one weight vector; 4 accumulator chains
#define DOT16(WV, SRC, BASE)                                                  \
    _Pragma("unroll")                                                         \
    for (int kk = 0; kk < 16; ++kk) {                                         \
        float s = __int_as_float(__builtin_amdgcn_readlane((SRC), (BASE)+kk));\
        acc[kk & 3] = fmaf(s, (WV)[kk], acc[kk & 3]);                         \
    }

    for (int t = 0; t < T; ++t) {
        // publish own half, fetch opposite half (double buffer -> 1 barrier/step)
        hbuf[t & 1][j] = hA;
        __syncthreads();
        const float hO = hbuf[t & 1][j ^ 64];
        const float xt = xs[t];

        // wave 0 lanes hold h[0..63] in hA, h[64..127] in hO; wave 1 swapped.
        const int src_lo = __float_as_int(wid ? hO : hA); // lane k has h[k]
        const int src_hi = __float_as_int(wid ? hA : hO); // lane k has h[64+k]

        vf4 acc;
        acc[0] = fmaf(xt, wih_j, bias_j);
        acc[1] = 0.0f; acc[2] = 0.0f; acc[3] = 0.0f;

        DOT16(w0, src_lo,  0)
        DOT16(w1, src_lo, 16)
        DOT16(w2, src_lo, 32)
        DOT16(w3, src_lo, 48)
        DOT16(w4, src_hi,  0)
        DOT16(w5, src_hi, 16)
        DOT16(w6, src_hi, 32)
        DOT16(w7, src_hi, 48)

        const float a = (acc[0] + acc[1]) + (acc[2] + acc[3]);
        // tanh(a) = 1 - 2/(exp(2a)+1), exp via v_exp_f32
        const float e = __expf(2.0f * a);
        hA = 1.0f - __fdividef(2.0f, e + 1.0f);
        // e==inf -> 2/inf = 0 -> 1 ; e==0 -> 1-2 = -1 : saturation correct
    }
#undef DOT16

    // --- y[b] = sum_j W_out[j] * h_last[j] + b_out
    float v = hA * W_out[j];
    #pragma unroll
    for (int off = 32; off >= 1; off >>= 1)
        v += __shfl_xor(v, off, 64);
    if (lane == 0) red[wid] = v;
    __syncthreads();
    if (j == 0) y[b] = red[0] + red[1] + b_out[0];
}

extern "C" void kernel_launch(void* const* d_in, const int* in_sizes, int n_in,
                              void* d_out, int out_size, void* d_ws, size_t ws_size,
                              hipStream_t stream)
{
    const float* x     = (const float*)d_in[0];
    const float* W_ih  = (const float*)d_in[1];
    const float* W_hh  = (const float*)d_in[2];
    const float* b_ih  = (const float*)d_in[3];
    const float* b_hh  = (const float*)d_in[4];
    const float* W_out = (const float*)d_in[5];
    const float* b_out = (const float*)d_in[6];
    float* y = (float*)d_out;

    const int T = T_STEPS;
    const int B = in_sizes[0] / T;   // x has B*T*1 elements

    rnn_scan_kernel<<<B, HID, 0, stream>>>(x, W_ih, W_hh, b_ih, b_hh,
                                           W_out, b_out, y, T);
}